// Round 8
// baseline (2297.950 us; speedup 1.0000x reference)
//
#include <hip/hip_runtime.h>
#include <hip/hip_bf16.h>

// GRU-D layer: B=256, T=512, D=128, H=256, fp32.
// R8 == R7 resubmit (R7 bench was an infra failure: container died twice;
// no kernel signal). Changes vs R6:
//  (a) proj3: single fused dot2-f16 kernel for xz/xr/xh (was 3 fp32
//      kernels, ~400us at 66TF; dot2 halves instrs, x staged once).
//  (b) scan: launch_bounds(512,1) -> U's 192 dwords live in arch VGPRs
//      (R6's (512,2) capped arch VGPRs at 256 -> compiler parked U in
//      AGPRs (VGPR_Count=128) and issued ~192 v_accvgpr_read/step junk =
//      the VALUBusy 46% mystery). 4-way acc chains + gate work split
//      across k-halves (half0: z, half1: r+rh).

static constexpr int Bb = 256;
static constexpr int Tt = 512;
static constexpr int Dd = 128;
static constexpr int Hh = 256;

typedef _Float16 half2_t __attribute__((ext_vector_type(2)));

__device__ __forceinline__ float dot2f(unsigned a, unsigned b, float c) {
  half2_t av, bv;
  __builtin_memcpy(&av, &a, 4);
  __builtin_memcpy(&bv, &b, 4);
#if __has_builtin(__builtin_amdgcn_fdot2)
  return __builtin_amdgcn_fdot2(av, bv, c, false);
#else
  return fmaf((float)av[1], (float)bv[1], fmaf((float)av[0], (float)bv[0], c));
#endif
}

__device__ __forceinline__ unsigned packh2(float lo, float hi) {
  half2_t hv;
  hv[0] = (_Float16)lo;
  hv[1] = (_Float16)hi;
  unsigned u;
  __builtin_memcpy(&u, &hv, 4);
  return u;
}

// ---------------------------------------------------------------------------
// Phase 1: fused projection, C_g[64,256] = x_tile[64,128] @ W_g + b_g, g=z,r,h
// f16-pair dot2. 256 thr: ty=tid>>5 (8 rows of 8), tx=tid&31 (32 cols of 8).
// ---------------------------------------------------------------------------
__global__ __launch_bounds__(256) void proj3_kernel(
    const float* __restrict__ x,
    const float* __restrict__ Wz, const float* __restrict__ Wr,
    const float* __restrict__ Wh,
    const float* __restrict__ bz, const float* __restrict__ br,
    const float* __restrict__ bh,
    float* __restrict__ oz, float* __restrict__ orr, float* __restrict__ oh)
{
  __shared__ unsigned xP[64][64];   // [k-pair][row] f16x2, 16 KB (x staged once)
  __shared__ unsigned wP[8][256];   // W k-pair slab, 8 KB

  const int tid = threadIdx.x;
  const int ty = tid >> 5;
  const int tx = tid & 31;
  const size_t brow = (size_t)blockIdx.x * 64;

  // stage x tile as f16 pairs (access pattern proven in R1 proj)
  #pragma unroll
  for (int it = 0; it < 8; ++it) {
    int idx = it * 256 + tid;
    int row = idx & 63;
    int kq  = idx >> 6;             // 0..31 float4 units
    float4 v = *(const float4*)(x + (brow + row) * Dd + kq * 4);
    xP[kq * 2 + 0][row] = packh2(v.x, v.y);
    xP[kq * 2 + 1][row] = packh2(v.z, v.w);
  }

  const float* Ws[3] = {Wz, Wr, Wh};
  const float* bs[3] = {bz, br, bh};
  float* os[3] = {oz, orr, oh};

  __syncthreads();

  for (int g = 0; g < 3; ++g) {
    float bv[8];
    *(float4*)&bv[0] = *(const float4*)(bs[g] + tx * 8);
    *(float4*)&bv[4] = *(const float4*)(bs[g] + tx * 8 + 4);

    float acc[8][8];
    #pragma unroll
    for (int i = 0; i < 8; ++i)
      #pragma unroll
      for (int jj = 0; jj < 8; ++jj) acc[i][jj] = 0.f;

    for (int s = 0; s < 8; ++s) {
      // stage W slab: 8 k-pairs (16 k) x 256 cols as f16x2
      #pragma unroll
      for (int it = 0; it < 2; ++it) {
        int qq  = it * 256 + tid;   // 0..511
        int kkp = qq >> 6;          // 0..7
        int c4  = (qq & 63) * 4;
        const float* wr0 = Ws[g] + (size_t)((s * 8 + kkp) * 2) * Hh + c4;
        float4 wa = *(const float4*)wr0;
        float4 wb = *(const float4*)(wr0 + Hh);
        uint4 pk;
        pk.x = packh2(wa.x, wb.x);
        pk.y = packh2(wa.y, wb.y);
        pk.z = packh2(wa.z, wb.z);
        pk.w = packh2(wa.w, wb.w);
        *(uint4*)&wP[kkp][c4] = pk;
      }
      __syncthreads();

      #pragma unroll
      for (int kkp = 0; kkp < 8; ++kkp) {
        unsigned xv[8], wv[8];
        *(uint4*)&xv[0] = *(const uint4*)&xP[s * 8 + kkp][ty * 8];
        *(uint4*)&xv[4] = *(const uint4*)&xP[s * 8 + kkp][ty * 8 + 4];
        *(uint4*)&wv[0] = *(const uint4*)&wP[kkp][tx * 8];
        *(uint4*)&wv[4] = *(const uint4*)&wP[kkp][tx * 8 + 4];
        #pragma unroll
        for (int i = 0; i < 8; ++i)
          #pragma unroll
          for (int jj = 0; jj < 8; ++jj)
            acc[i][jj] = dot2f(xv[i], wv[jj], acc[i][jj]);
      }
      __syncthreads();
    }

    float* of = os[g];
    #pragma unroll
    for (int i = 0; i < 8; ++i) {
      size_t ro = (brow + (size_t)ty * 8 + i) * Hh + tx * 8;
      float4 a{acc[i][0] + bv[0], acc[i][1] + bv[1],
               acc[i][2] + bv[2], acc[i][3] + bv[3]};
      float4 c{acc[i][4] + bv[4], acc[i][5] + bv[5],
               acc[i][6] + bv[6], acc[i][7] + bv[7]};
      *(float4*)(of + ro) = a;
      *(float4*)(of + ro + 4) = c;
    }
  }
}

// ---------------------------------------------------------------------------
// Phase 2: dot2 scan. 1 block = 1 batch, 512 thr = 256 cols x 2 k-halves.
// launch_bounds(512,1): VGPR cap 512 -> U's 192 dwords stay in arch VGPRs.
// Gate split: half0 computes z; half1 computes r + rh (hd from LDS f16).
// ---------------------------------------------------------------------------
__global__ __launch_bounds__(512, 1) void gru_scan_dot2(
    const float* __restrict__ xz, const float* __restrict__ xr,
    const float* __restrict__ hdecay,
    const float* __restrict__ Uz, const float* __restrict__ Ur,
    const float* __restrict__ Uh, float* __restrict__ out)
{
  const int tid  = threadIdx.x;
  const int j    = tid & (Hh - 1);   // output column
  const int half = tid >> 8;         // k-half
  const int k0   = half << 7;
  const int b    = blockIdx.x;

  __shared__ unsigned hdp[128];      // f16x2 pairs of h_dec
  __shared__ unsigned rhp[128];      // f16x2 pairs of r*h_dec
  __shared__ float pz1[Hh];          // half1's z-partial
  __shared__ float pr0[Hh];          // half0's r-partial
  __shared__ float ph1[Hh];          // half1's h-partial

  // ---- U column-halves as f16 pairs: 3 x 64 = 192 VGPRs ----
  unsigned uz[64], ur[64], uh[64];
  {
    const float* uzp = Uz + (size_t)k0 * Hh + j;
    const float* urp = Ur + (size_t)k0 * Hh + j;
    const float* uhp = Uh + (size_t)k0 * Hh + j;
    #pragma unroll
    for (int m = 0; m < 64; ++m) {
      uz[m] = packh2(uzp[(size_t)(2 * m) * Hh], uzp[(size_t)(2 * m + 1) * Hh]);
      ur[m] = packh2(urp[(size_t)(2 * m) * Hh], urp[(size_t)(2 * m + 1) * Hh]);
      uh[m] = packh2(uhp[(size_t)(2 * m) * Hh], uhp[(size_t)(2 * m + 1) * Hh]);
    }
  }

  if (tid < 128) hdp[tid] = 0u;      // h0 = 0

  const size_t bbase = (size_t)b * Tt * Hh;
  const int    hbase = b * Tt;

  float hd = 0.f;                    // half0: fp32 h_dec[j]
  float xz_c = 0.f, xr_c = 0.f, xh_c = 0.f, dec_n = 0.f;

  // prologue: half0 loads xz,xh,dec; half1 loads xr
  if (half == 0) {
    xz_c = xz[bbase + j];
    xh_c = out[bbase + j];
    dec_n = hdecay[hbase + 1];
  } else {
    xr_c = xr[bbase + j];
  }
  __syncthreads();

  for (int t = 0; t < Tt; ++t) {
    // ---- prefetch t+1 (clamped; junk at t=Tt-1 never used) ----
    float xz_n = 0.f, xr_n = 0.f, xh_n = 0.f, dec_n2 = 0.f;
    {
      const int tp = (t + 1 < Tt) ? t + 1 : Tt - 1;
      const size_t bp = bbase + (size_t)tp * Hh + j;
      if (half == 0) {
        const int tq = (t + 2 < Tt) ? t + 2 : Tt - 1;
        xz_n = xz[bp];
        xh_n = out[bp];
        dec_n2 = hdecay[hbase + tq];
      } else {
        xr_n = xr[bp];
      }
    }

    // ---- A: z/r dots over own k-half, 4-way acc chains ----
    float az[4] = {0.f, 0.f, 0.f, 0.f};
    float ar[4] = {0.f, 0.f, 0.f, 0.f};
    #pragma unroll
    for (int g4 = 0; g4 < 4; ++g4) {
      #pragma unroll
      for (int m4 = 0; m4 < 4; ++m4) {
        uint4 ha = *(const uint4*)&hdp[(half << 6) + g4 * 16 + m4 * 4];
        const int mb = g4 * 16 + m4 * 4;
        az[g4] = dot2f(ha.x, uz[mb + 0], az[g4]);
        az[g4] = dot2f(ha.y, uz[mb + 1], az[g4]);
        az[g4] = dot2f(ha.z, uz[mb + 2], az[g4]);
        az[g4] = dot2f(ha.w, uz[mb + 3], az[g4]);
        ar[g4] = dot2f(ha.x, ur[mb + 0], ar[g4]);
        ar[g4] = dot2f(ha.y, ur[mb + 1], ar[g4]);
        ar[g4] = dot2f(ha.z, ur[mb + 2], ar[g4]);
        ar[g4] = dot2f(ha.w, ur[mb + 3], ar[g4]);
      }
    }
    const float azs = (az[0] + az[1]) + (az[2] + az[3]);
    const float ars = (ar[0] + ar[1]) + (ar[2] + ar[3]);
    if (half) pz1[j] = azs; else pr0[j] = ars;
    __syncthreads();

    // ---- B: half0 -> z gate; half1 -> r gate + rh pairs ----
    float z = 0.f;
    if (half == 0) {
      float zs = xz_c + azs + pz1[j];
      z = 1.f / (1.f + __expf(-zs));
    } else {
      float rs = xr_c + ars + pr0[j];
      float r = 1.f / (1.f + __expf(-rs));
      unsigned hp2 = hdp[j >> 1];
      half2_t hh;
      __builtin_memcpy(&hh, &hp2, 4);
      float hdl = (float)hh[j & 1];
      float rh = r * hdl;
      float nb = __shfl_xor(rh, 1, 64);
      if ((j & 1) == 0) rhp[j >> 1] = packh2(rh, nb);
    }
    __syncthreads();

    // ---- C: h dots over own k-half ----
    float ah[4] = {0.f, 0.f, 0.f, 0.f};
    #pragma unroll
    for (int g4 = 0; g4 < 4; ++g4) {
      #pragma unroll
      for (int m4 = 0; m4 < 4; ++m4) {
        uint4 ra = *(const uint4*)&rhp[(half << 6) + g4 * 16 + m4 * 4];
        const int mb = g4 * 16 + m4 * 4;
        ah[g4] = dot2f(ra.x, uh[mb + 0], ah[g4]);
        ah[g4] = dot2f(ra.y, uh[mb + 1], ah[g4]);
        ah[g4] = dot2f(ra.z, uh[mb + 2], ah[g4]);
        ah[g4] = dot2f(ra.w, uh[mb + 3], ah[g4]);
      }
    }
    const float ahs = (ah[0] + ah[1]) + (ah[2] + ah[3]);
    if (half) ph1[j] = ahs;
    __syncthreads();

    // ---- D: half0 combines, stores h_t, writes h_dec(t+1) pairs ----
    if (half == 0) {
      float hs = xh_c + ahs + ph1[j];
      float ex = __expf(2.f * hs);          // tanh = 1 - 2/(e^{2x}+1)
      float hp = 1.f - 2.f / (ex + 1.f);
      float hn = (1.f - z) * hd + z * hp;
      out[bbase + (size_t)t * Hh + j] = hn;
      hd = dec_n * hn;
      float nb = __shfl_xor(hd, 1, 64);
      if ((j & 1) == 0) hdp[j >> 1] = packh2(hd, nb);
    }
    // rotate prefetch (both halves; unused slots harmless)
    xz_c = xz_n; xr_c = xr_n; xh_c = xh_n; dec_n = dec_n2;
    __syncthreads();
  }
}

// ---------------------------------------------------------------------------
extern "C" void kernel_launch(void* const* d_in, const int* in_sizes, int n_in,
                              void* d_out, int out_size, void* d_ws, size_t ws_size,
                              hipStream_t stream) {
  const float* x   = (const float*)d_in[0];
  const float* hdc = (const float*)d_in[1];
  const float* Wr  = (const float*)d_in[2];
  const float* Wz  = (const float*)d_in[3];
  const float* Wh  = (const float*)d_in[4];
  const float* Ur  = (const float*)d_in[5];
  const float* Uz  = (const float*)d_in[6];
  const float* Uh  = (const float*)d_in[7];
  const float* br  = (const float*)d_in[8];
  const float* bz  = (const float*)d_in[9];
  const float* bh  = (const float*)d_in[10];
  float* out = (float*)d_out;

  const size_t bth = (size_t)Bb * Tt * Hh;   // 33,554,432
  float* wsz = (float*)d_ws;
  float* wsr = wsz + bth;

  // fused projections: xz->ws, xr->ws, xh->out
  proj3_kernel<<<dim3(2048), dim3(256), 0, stream>>>(
      x, Wz, Wr, Wh, bz, br, bh, wsz, wsr, out);

  gru_scan_dot2<<<dim3(Bb), dim3(512), 0, stream>>>(
      wsz, wsr, hdc, Uz, Ur, Uh, out);
}

// Round 9
// 1367.328 us; speedup vs baseline: 1.6806x; 1.6806x over previous
//
#include <hip/hip_runtime.h>
#include <hip/hip_bf16.h>

// GRU-D layer: B=256, T=512, D=128, H=256, fp32.
// R9: gate-parallel dot2 scan. R8 lesson: a 512-thr block pins arch-VGPR
// cap at 256 (8 waves must co-reside); U at 192 dwords/thread + working
// set never fits -> compiler parks U in AGPRs (VGPR_Count=128) and every
// dot2 pays a move. Fix the FOOTPRINT: 768 thr = 256 cols x 3 gates, each
// thread owns ONE U_g column = 128 dwords -> ~155 regs total < 170 cap
// (launch_bounds(768,3) = 3 waves/SIMD). 2 barriers/step (was 4).
// proj3 (fused f16 dot2 projection) unchanged from R8.

static constexpr int Bb = 256;
static constexpr int Tt = 512;
static constexpr int Dd = 128;
static constexpr int Hh = 256;

typedef _Float16 half2_t __attribute__((ext_vector_type(2)));

__device__ __forceinline__ float dot2f(unsigned a, unsigned b, float c) {
  half2_t av, bv;
  __builtin_memcpy(&av, &a, 4);
  __builtin_memcpy(&bv, &b, 4);
#if __has_builtin(__builtin_amdgcn_fdot2)
  return __builtin_amdgcn_fdot2(av, bv, c, false);
#else
  return fmaf((float)av[1], (float)bv[1], fmaf((float)av[0], (float)bv[0], c));
#endif
}

__device__ __forceinline__ unsigned packh2(float lo, float hi) {
  half2_t hv;
  hv[0] = (_Float16)lo;
  hv[1] = (_Float16)hi;
  unsigned u;
  __builtin_memcpy(&u, &hv, 4);
  return u;
}

// ---------------------------------------------------------------------------
// Phase 1: fused projection (unchanged from R8; validated)
// ---------------------------------------------------------------------------
__global__ __launch_bounds__(256) void proj3_kernel(
    const float* __restrict__ x,
    const float* __restrict__ Wz, const float* __restrict__ Wr,
    const float* __restrict__ Wh,
    const float* __restrict__ bz, const float* __restrict__ br,
    const float* __restrict__ bh,
    float* __restrict__ oz, float* __restrict__ orr, float* __restrict__ oh)
{
  __shared__ unsigned xP[64][64];
  __shared__ unsigned wP[8][256];

  const int tid = threadIdx.x;
  const int ty = tid >> 5;
  const int tx = tid & 31;
  const size_t brow = (size_t)blockIdx.x * 64;

  #pragma unroll
  for (int it = 0; it < 8; ++it) {
    int idx = it * 256 + tid;
    int row = idx & 63;
    int kq  = idx >> 6;
    float4 v = *(const float4*)(x + (brow + row) * Dd + kq * 4);
    xP[kq * 2 + 0][row] = packh2(v.x, v.y);
    xP[kq * 2 + 1][row] = packh2(v.z, v.w);
  }

  const float* Ws[3] = {Wz, Wr, Wh};
  const float* bs[3] = {bz, br, bh};
  float* os[3] = {oz, orr, oh};

  __syncthreads();

  for (int g = 0; g < 3; ++g) {
    float bv[8];
    *(float4*)&bv[0] = *(const float4*)(bs[g] + tx * 8);
    *(float4*)&bv[4] = *(const float4*)(bs[g] + tx * 8 + 4);

    float acc[8][8];
    #pragma unroll
    for (int i = 0; i < 8; ++i)
      #pragma unroll
      for (int jj = 0; jj < 8; ++jj) acc[i][jj] = 0.f;

    for (int s = 0; s < 8; ++s) {
      #pragma unroll
      for (int it = 0; it < 2; ++it) {
        int qq  = it * 256 + tid;
        int kkp = qq >> 6;
        int c4  = (qq & 63) * 4;
        const float* wr0 = Ws[g] + (size_t)((s * 8 + kkp) * 2) * Hh + c4;
        float4 wa = *(const float4*)wr0;
        float4 wb = *(const float4*)(wr0 + Hh);
        uint4 pk;
        pk.x = packh2(wa.x, wb.x);
        pk.y = packh2(wa.y, wb.y);
        pk.z = packh2(wa.z, wb.z);
        pk.w = packh2(wa.w, wb.w);
        *(uint4*)&wP[kkp][c4] = pk;
      }
      __syncthreads();

      #pragma unroll
      for (int kkp = 0; kkp < 8; ++kkp) {
        unsigned xv[8], wv[8];
        *(uint4*)&xv[0] = *(const uint4*)&xP[s * 8 + kkp][ty * 8];
        *(uint4*)&xv[4] = *(const uint4*)&xP[s * 8 + kkp][ty * 8 + 4];
        *(uint4*)&wv[0] = *(const uint4*)&wP[kkp][tx * 8];
        *(uint4*)&wv[4] = *(const uint4*)&wP[kkp][tx * 8 + 4];
        #pragma unroll
        for (int i = 0; i < 8; ++i)
          #pragma unroll
          for (int jj = 0; jj < 8; ++jj)
            acc[i][jj] = dot2f(xv[i], wv[jj], acc[i][jj]);
      }
      __syncthreads();
    }

    float* of = os[g];
    #pragma unroll
    for (int i = 0; i < 8; ++i) {
      size_t ro = (brow + (size_t)ty * 8 + i) * Hh + tx * 8;
      float4 a{acc[i][0] + bv[0], acc[i][1] + bv[1],
               acc[i][2] + bv[2], acc[i][3] + bv[3]};
      float4 c{acc[i][4] + bv[4], acc[i][5] + bv[5],
               acc[i][6] + bv[6], acc[i][7] + bv[7]};
      *(float4*)(of + ro) = a;
      *(float4*)(of + ro + 4) = c;
    }
  }
}

// ---------------------------------------------------------------------------
// Phase 2: gate-parallel dot2 scan. 1 block = 1 batch.
// 768 thr = 256 cols x 3 gates (z,r,h); wave-uniform gate (tid>>8).
// U_g column per thread: 128 f16-pair dwords in arch VGPRs.
// Step: [A: z,r dots + gates -> zbuf,rhp] bar [B: h dots + combine -> out,hdp] bar
// ---------------------------------------------------------------------------
__global__ __launch_bounds__(768, 3) void gru_scan_g3(
    const float* __restrict__ xz, const float* __restrict__ xr,
    const float* __restrict__ hdecay,
    const float* __restrict__ Uz, const float* __restrict__ Ur,
    const float* __restrict__ Uh, float* __restrict__ out)
{
  const int tid = threadIdx.x;
  const int j   = tid & 255;        // output column
  const int g   = tid >> 8;         // 0=z, 1=r, 2=h (wave-uniform)
  const int b   = blockIdx.x;

  __shared__ unsigned hdp[128];     // f16x2 k-pairs of h_dec
  __shared__ unsigned rhp[128];     // f16x2 k-pairs of r*h_dec
  __shared__ float    zbuf[256];    // z gate (f32)

  // ---- own U_g column as f16 k-pairs: 128 dwords ----
  const float* Ug = (g == 0) ? Uz : (g == 1) ? Ur : Uh;
  unsigned uu[128];
  #pragma unroll
  for (int m = 0; m < 128; ++m)
    uu[m] = packh2(Ug[(size_t)(2 * m) * Hh + j],
                   Ug[(size_t)(2 * m + 1) * Hh + j]);

  if (tid < 128) hdp[tid] = 0u;     // h0 = 0

  const size_t bbase = (size_t)b * Tt * Hh;
  const int    hbase = b * Tt;

  float hd = 0.f;                   // fp32 h_dec state (g==2 lanes)
  float xc = 0.f, xn = 0.f;         // own input, current/next
  float dec_n = 0.f, dec_n2 = 0.f;

  // prologue: t=0 inputs
  if (g == 0)      xc = xz[bbase + j];
  else if (g == 1) xc = xr[bbase + j];
  else { xc = out[bbase + j]; dec_n = hdecay[hbase + 1]; }
  __syncthreads();

  for (int t = 0; t < Tt; ++t) {
    // ---- prefetch t+1 (clamped; junk at t=Tt-1 never used) ----
    {
      const int tp = (t + 1 < Tt) ? t + 1 : Tt - 1;
      const size_t bp = bbase + (size_t)tp * Hh + j;
      if (g == 0)      xn = xz[bp];
      else if (g == 1) xn = xr[bp];
      else {
        xn = out[bp];
        dec_n2 = hdecay[hbase + ((t + 2 < Tt) ? t + 2 : Tt - 1)];
      }
    }

    // ---- phase A: z,r waves dot h_dec over full k ----
    if (g < 2) {
      float acc[4] = {0.f, 0.f, 0.f, 0.f};
      #pragma unroll
      for (int u4 = 0; u4 < 32; ++u4) {
        uint4 hp4 = *(const uint4*)&hdp[u4 * 4];
        const int mb = u4 * 4;
        float a = acc[u4 & 3];
        a = dot2f(hp4.x, uu[mb + 0], a);
        a = dot2f(hp4.y, uu[mb + 1], a);
        a = dot2f(hp4.z, uu[mb + 2], a);
        a = dot2f(hp4.w, uu[mb + 3], a);
        acc[u4 & 3] = a;
      }
      float s = (acc[0] + acc[1]) + (acc[2] + acc[3]);
      if (g == 0) {
        zbuf[j] = 1.f / (1.f + __expf(-(xc + s)));
      } else {
        float rv = 1.f / (1.f + __expf(-(xc + s)));
        unsigned hp2 = hdp[j >> 1];
        half2_t hh;
        __builtin_memcpy(&hh, &hp2, 4);
        float rh = rv * (float)hh[j & 1];
        float nb = __shfl_xor(rh, 1, 64);
        if ((j & 1) == 0) rhp[j >> 1] = packh2(rh, nb);
      }
    }
    __syncthreads();   // zbuf, rhp visible; hdp reads done

    // ---- phase B: h waves dot r*h_dec; combine; advance state ----
    if (g == 2) {
      float acc[4] = {0.f, 0.f, 0.f, 0.f};
      #pragma unroll
      for (int u4 = 0; u4 < 32; ++u4) {
        uint4 rp4 = *(const uint4*)&rhp[u4 * 4];
        const int mb = u4 * 4;
        float a = acc[u4 & 3];
        a = dot2f(rp4.x, uu[mb + 0], a);
        a = dot2f(rp4.y, uu[mb + 1], a);
        a = dot2f(rp4.z, uu[mb + 2], a);
        a = dot2f(rp4.w, uu[mb + 3], a);
        acc[u4 & 3] = a;
      }
      float s  = (acc[0] + acc[1]) + (acc[2] + acc[3]);
      float hs = xc + s;
      float ex = __expf(2.f * hs);            // tanh = 1 - 2/(e^{2x}+1)
      float hp = 1.f - 2.f / (ex + 1.f);
      float zv = zbuf[j];
      float hn = (1.f - zv) * hd + zv * hp;
      out[bbase + (size_t)t * Hh + j] = hn;
      hd = dec_n * hn;                        // fp32 state chain
      float nb = __shfl_xor(hd, 1, 64);
      if ((j & 1) == 0) hdp[j >> 1] = packh2(hd, nb);
    }
    __syncthreads();   // hdp(t+1) visible

    xc = xn;
    dec_n = dec_n2;
  }
}

// ---------------------------------------------------------------------------
extern "C" void kernel_launch(void* const* d_in, const int* in_sizes, int n_in,
                              void* d_out, int out_size, void* d_ws, size_t ws_size,
                              hipStream_t stream) {
  const float* x   = (const float*)d_in[0];
  const float* hdc = (const float*)d_in[1];
  const float* Wr  = (const float*)d_in[2];
  const float* Wz  = (const float*)d_in[3];
  const float* Wh  = (const float*)d_in[4];
  const float* Ur  = (const float*)d_in[5];
  const float* Uz  = (const float*)d_in[6];
  const float* Uh  = (const float*)d_in[7];
  const float* br  = (const float*)d_in[8];
  const float* bz  = (const float*)d_in[9];
  const float* bh  = (const float*)d_in[10];
  float* out = (float*)d_out;

  const size_t bth = (size_t)Bb * Tt * Hh;   // 33,554,432
  float* wsz = (float*)d_ws;
  float* wsr = wsz + bth;

  // fused projections: xz->ws, xr->ws, xh->out
  proj3_kernel<<<dim3(2048), dim3(256), 0, stream>>>(
      x, Wz, Wr, Wh, bz, br, bh, wsz, wsr, out);

  gru_scan_g3<<<dim3(Bb), dim3(768), 0, stream>>>(
      wsz, wsr, hdc, Uz, Ur, Uh, out);
}